// Round 1
// baseline (131.617 us; speedup 1.0000x reference)
//
#include <hip/hip_runtime.h>

#define NGRAPH 128
#define NBLK   512
#define BS     256

__global__ __launch_bounds__(BS) void edgevar_stage1(
    const float* __restrict__ pos,
    const int*   __restrict__ ei,
    const int*   __restrict__ batch,
    float*       __restrict__ part,
    int E) {
  __shared__ float s_acc[2 * NGRAPH];   // [0,128): sums, [128,256): counts
  for (int i = threadIdx.x; i < 2 * NGRAPH; i += BS) s_acc[i] = 0.f;
  __syncthreads();

  const int tid = blockIdx.x * BS + threadIdx.x;
  const int nth = NBLK * BS;
  const int E4  = E >> 2;
  const int4*   __restrict__ s4 = (const int4*)ei;
  const int4*   __restrict__ d4 = (const int4*)(ei + E);
  const float2* __restrict__ p2 = (const float2*)pos;

  for (int i = tid; i < E4; i += nth) {
    int4 s = s4[i];
    int4 d = d4[i];
    int ss[4] = {s.x, s.y, s.z, s.w};
    int dd[4] = {d.x, d.y, d.z, d.w};
#pragma unroll
    for (int k = 0; k < 4; ++k) {
      float2 a = p2[ss[k]];
      float2 b = p2[dd[k]];
      float dx = b.x - a.x, dy = b.y - a.y;
      float eu = sqrtf(dx * dx + dy * dy);
      float v  = eu - 1.f;
      v *= v;
      int g = batch[ss[k]];
      atomicAdd(&s_acc[g], v);
      atomicAdd(&s_acc[NGRAPH + g], 1.f);
    }
  }
  // tail (E not divisible by 4)
  for (int e = (E4 << 2) + tid; e < E; e += nth) {
    int sn = ei[e];
    int dn = ei[e + E];
    float2 a = p2[sn];
    float2 b = p2[dn];
    float dx = b.x - a.x, dy = b.y - a.y;
    float eu = sqrtf(dx * dx + dy * dy);
    float v  = eu - 1.f;
    v *= v;
    int g = batch[sn];
    atomicAdd(&s_acc[g], v);
    atomicAdd(&s_acc[NGRAPH + g], 1.f);
  }

  __syncthreads();
  float* dst = part + (size_t)blockIdx.x * (2 * NGRAPH);
  for (int i = threadIdx.x; i < 2 * NGRAPH; i += BS) dst[i] = s_acc[i];
}

__global__ __launch_bounds__(2 * NGRAPH) void edgevar_stage2(
    const float* __restrict__ part,
    float*       __restrict__ out) {
  const int t = threadIdx.x;
  float acc = 0.f;
#pragma unroll 8
  for (int b = 0; b < NBLK; ++b) acc += part[(size_t)b * (2 * NGRAPH) + t];

  __shared__ float s[2 * NGRAPH];
  s[t] = acc;
  __syncthreads();

  __shared__ float red[NGRAPH];
  if (t < NGRAPH) {
    float sum = s[t];
    float cnt = s[NGRAPH + t];
    red[t] = sum / fmaxf(cnt, 1.f);
  }
  __syncthreads();
  if (t < 64) {
    float v = red[t] + red[t + 64];
    for (int off = 32; off; off >>= 1) v += __shfl_down(v, off);
    if (t == 0) out[0] = v * (1.0f / NGRAPH);
  }
}

extern "C" void kernel_launch(void* const* d_in, const int* in_sizes, int n_in,
                              void* d_out, int out_size, void* d_ws, size_t ws_size,
                              hipStream_t stream) {
  const float* pos   = (const float*)d_in[0];
  const int*   ei    = (const int*)d_in[1];
  const int*   batch = (const int*)d_in[2];
  float*       out   = (float*)d_out;
  float*       part  = (float*)d_ws;   // NBLK * 256 floats = 512 KB
  const int E = in_sizes[1] / 2;

  hipLaunchKernelGGL(edgevar_stage1, dim3(NBLK), dim3(BS), 0, stream,
                     pos, ei, batch, part, E);
  hipLaunchKernelGGL(edgevar_stage2, dim3(1), dim3(2 * NGRAPH), 0, stream,
                     part, out);
}